// Round 5
// baseline (264.843 us; speedup 1.0000x reference)
//
#include <hip/hip_runtime.h>
#include <hip/hip_bf16.h>

// Dense FFN: out = relu(x @ w1 + b1) @ w2 + b2
// x  [8192,1024] f32, w1 [1024,4096] f32, b1 [4096] f32,
// w2 [4096,1024] f32, b2 [1024] f32, out [8192,1024] f32.
// R5: register-prefetch K-loop.  The measured limiter (R2-R4) is the
// vmcnt(0) drain at the staging barrier with few resident blocks.  Replace
// global_load_lds with: global loads -> VGPRs issued right after the LDS
// buffer becomes safe, ds_write one full compute-phase later.  The
// compiler's mandatory vmcnt(0)-before-barrier then waits on loads that
// have been in flight for the whole compute phase (per-wave hiding, works
// even at 1-2 blocks/CU).  Single 32KB LDS buffer, 128x128 tile, BK=64,
// XOR chunk swizzle now applied on the ds_write side (frag reads unchanged,
// 0 conflicts as verified in R2), XCD-aware block swizzle, fused prep.

typedef __bf16 bf16;
typedef __bf16 bf16x4 __attribute__((ext_vector_type(4)));
typedef __bf16 bf16x8 __attribute__((ext_vector_type(8)));
typedef float  f32x4  __attribute__((ext_vector_type(4)));

#define BM 128
#define BN 128
#define BK 64

// ---------------------------------------------------------------------------
// fused prep: cast x -> bf16 ; transpose+cast w1, w2 -> [N][K] bf16.
__device__ __forceinline__ void transpose_tile(
    const float* __restrict__ in, bf16* __restrict__ out,
    int K, int N, int bx, int by, int t, bf16 (*tile)[72])
{
    const int k0 = by * 64;
    const int n0 = bx * 64;
    const int lr = t >> 4;          // 0..15
    const int lc = (t & 15) << 2;   // 0,4,..60
#pragma unroll
    for (int p = 0; p < 4; ++p) {
        int k = p * 16 + lr;
        float4 v = *(const float4*)(in + (size_t)(k0 + k) * N + n0 + lc);
        tile[lc + 0][k] = (bf16)v.x;
        tile[lc + 1][k] = (bf16)v.y;
        tile[lc + 2][k] = (bf16)v.z;
        tile[lc + 3][k] = (bf16)v.w;
    }
    __syncthreads();
    const int wr = t >> 3;          // 0..31
    const int wc = (t & 7) << 3;    // 0,8,..56
#pragma unroll
    for (int p = 0; p < 2; ++p) {
        int n = p * 32 + wr;
        *(bf16x8*)(out + (size_t)(n0 + n) * K + k0 + wc) =
            *(const bf16x8*)&tile[n][wc];
    }
}

__global__ __launch_bounds__(256) void prep(
    const float* __restrict__ x,  bf16* __restrict__ xb,
    const float* __restrict__ w1, bf16* __restrict__ w1t,
    const float* __restrict__ w2, bf16* __restrict__ w2t)
{
    __shared__ __align__(16) bf16 tile[64][72];
    const int b = blockIdx.x;
    const int t = threadIdx.x;
    if (b < 8192) {                      // cast x: 4 f32/thread
        int i = b * 256 + t;
        float4 v = ((const float4*)x)[i];
        bf16x4 o;
        o.x = (bf16)v.x; o.y = (bf16)v.y; o.z = (bf16)v.z; o.w = (bf16)v.w;
        ((bf16x4*)xb)[i] = o;
    } else if (b < 9216) {               // w1 [1024][4096] -> w1t [4096][1024]
        int b2 = b - 8192;
        transpose_tile(w1, w1t, 1024, 4096, b2 & 63, b2 >> 6, t, tile);
    } else {                             // w2 [4096][1024] -> w2t [1024][4096]
        int b2 = b - 9216;
        transpose_tile(w2, w2t, 4096, 1024, b2 & 15, b2 >> 4, t, tile);
    }
}

// ---------------------------------------------------------------------------
// C[m][n] = sum_k A[m][k] * Bt[n][k]  (+bias, opt relu)
// A [M][K] bf16, Bt [N][K] bf16.  Block = 256 thr = 4 waves, tile 128x128,
// BK=64.  Wave w -> 64x64 subtile (w>>1, w&1).  16x16x32 bf16 MFMA.
// K-loop: register-prefetch pipeline, single LDS buffer:
//   gload(0); loop { barrier; ds_write; barrier; gload(t+1); compute(t); }
// LDS row r stores global chunk q at slot q^(r&7)  ->  frag reads use
// ch = ((h*4+quad)^r7)*16B, bank-conflict-free (verified R2).
template <int FUSE_RELU_BF16>
__global__ __launch_bounds__(256, 3) void gemm_bt(
    const bf16* __restrict__ A, const bf16* __restrict__ Bt,
    const float* __restrict__ bias, void* __restrict__ Cout,
    int M, int N, int K, int nx)
{
    __shared__ __align__(16) bf16 As[BM * BK];   // 16 KiB
    __shared__ __align__(16) bf16 Bs[BN * BK];   // 16 KiB

    // XCD-aware block decode: M-strips striped across XCDs, N fastest
    const int lid = blockIdx.x;
    const int xcd = lid & 7;
    const int j   = lid >> 3;
    const int bx  = j % nx;
    const int by  = (j / nx) * 8 + xcd;

    const int tid  = threadIdx.x;
    const int wave = tid >> 6;
    const int lane = tid & 63;

    // staging: wave w covers A rows [w*32, w*32+32), B rows likewise.
    // one b128 load = 8 rows x 64 elems: lane -> row l8, chunk c8 (16B).
    const int l8  = lane >> 3;
    const int c8  = lane & 7;
    const size_t K_ = (size_t)K;
    const size_t g8 = 8 * K_;            // 8-row stride

    const bf16* pA = A  + ((size_t)by * BM + wave * 32 + l8) * K_ + c8 * 8;
    const bf16* pB = Bt + ((size_t)bx * BN + wave * 32 + l8) * K_ + c8 * 8;
    // LDS write: row (wave*32+g*8+l8), slot c8^l8 (row&7 == l8 here)
    const int wofs = (wave * 32 + l8) * BK + ((c8 ^ l8) << 3);

    const int wm   = (wave >> 1) << 6;
    const int wn   = (wave & 1) << 6;
    const int quad = lane >> 4;
    const int r    = lane & 15;
    const int r7   = lane & 7;

    f32x4 acc[4][4] = {};
    bf16x8 rA[4], rB[4];

    auto gload = [&]() {
#pragma unroll
        for (int g = 0; g < 4; ++g) {
            rA[g] = *(const bf16x8*)(pA + g * g8);
            rB[g] = *(const bf16x8*)(pB + g * g8);
        }
        pA += BK; pB += BK;
    };
    auto lwrite = [&]() {
#pragma unroll
        for (int g = 0; g < 4; ++g) {
            *(bf16x8*)&As[wofs + g * (8 * BK)] = rA[g];
            *(bf16x8*)&Bs[wofs + g * (8 * BK)] = rB[g];
        }
    };
    auto compute = [&]() {
#pragma unroll
        for (int h = 0; h < 2; ++h) {
            const int ch = ((h * 4 + quad) ^ r7) << 3;
            bf16x8 af[4], bfr[4];
#pragma unroll
            for (int i = 0; i < 4; ++i)
                af[i] = *(const bf16x8*)&As[(wm + i * 16 + r) * BK + ch];
#pragma unroll
            for (int jj = 0; jj < 4; ++jj)
                bfr[jj] = *(const bf16x8*)&Bs[(wn + jj * 16 + r) * BK + ch];
#pragma unroll
            for (int i = 0; i < 4; ++i)
#pragma unroll
                for (int jj = 0; jj < 4; ++jj)
                    acc[i][jj] = __builtin_amdgcn_mfma_f32_16x16x32_bf16(
                        af[i], bfr[jj], acc[i][jj], 0, 0, 0);
        }
    };

    const int T = K / BK;
    gload();                       // tile 0 -> regs
    for (int t = 0; t < T; ++t) {
        __syncthreads();           // (A) LDS free; vmcnt drain = regs ready
        lwrite();
        __syncthreads();           // (B) tile t visible (lgkm only)
        if (t + 1 < T) gload();    // t+1 in flight for the whole compute
        compute();
    }

    // epilogue: C/D layout col = lane&15, row = quad*4 + reg
    const int m_base = by * BM + wm + quad * 4;
    const int n_base = bx * BN + wn + r;
    float bv[4];
#pragma unroll
    for (int jj = 0; jj < 4; ++jj) bv[jj] = bias[n_base + jj * 16];

    if (FUSE_RELU_BF16) {
        bf16* Cb = (bf16*)Cout;
#pragma unroll
        for (int i = 0; i < 4; ++i) {
#pragma unroll
            for (int p = 0; p < 4; ++p) {
                size_t row = (size_t)(m_base + i * 16 + p) * (size_t)N;
#pragma unroll
                for (int jj = 0; jj < 4; ++jj) {
                    float v = acc[i][jj][p] + bv[jj];
                    v = v > 0.f ? v : 0.f;
                    Cb[row + n_base + jj * 16] = (bf16)v;
                }
            }
        }
    } else {
        float* Cf = (float*)Cout;
#pragma unroll
        for (int i = 0; i < 4; ++i) {
#pragma unroll
            for (int p = 0; p < 4; ++p) {
                size_t row = (size_t)(m_base + i * 16 + p) * (size_t)N;
#pragma unroll
                for (int jj = 0; jj < 4; ++jj) {
                    Cf[row + n_base + jj * 16] = acc[i][jj][p] + bv[jj];
                }
            }
        }
    }
}

// ---------------------------------------------------------------------------
extern "C" void kernel_launch(void* const* d_in, const int* in_sizes, int n_in,
                              void* d_out, int out_size, void* d_ws, size_t ws_size,
                              hipStream_t stream)
{
    const float* x  = (const float*)d_in[0];  // [8192,1024]
    const float* w1 = (const float*)d_in[1];  // [1024,4096]
    const float* b1 = (const float*)d_in[2];  // [4096]
    const float* w2 = (const float*)d_in[3];  // [4096,1024]
    const float* b2 = (const float*)d_in[4];  // [1024]
    float* out = (float*)d_out;               // [8192,1024]

    const int M = 8192, D = 1024, W = 4096;

    char* ws = (char*)d_ws;
    bf16* xb  = (bf16*)(ws);                           // 16 MiB: [8192,1024]
    bf16* w1t = (bf16*)(ws + (size_t)(16 << 20));      //  8 MiB: [4096,1024]
    bf16* w2t = (bf16*)(ws + (size_t)(24 << 20));      //  8 MiB: [1024,4096]
    bf16* h   = (bf16*)(ws + (size_t)(32 << 20));      // 64 MiB: [8192,4096]

    // 1. fused prep: cast x, transpose+cast w1 & w2
    prep<<<8192 + 1024 + 1024, 256, 0, stream>>>(x, xb, w1, w1t, w2, w2t);

    // 2. h = relu(xb @ w1 + b1), bf16  [M][W]   grid 2048
    gemm_bt<1><<<(W / BN) * (M / BM), 256, 0, stream>>>(
        xb, w1t, b1, (void*)h, M, W, D, W / BN);

    // 3. out = h @ w2 + b2, f32  [M][D]         grid 512
    gemm_bt<0><<<(D / BN) * (M / BM), 256, 0, stream>>>(
        h, w2t, b2, (void*)out, M, D, W, D / BN);
}